// Round 1
// baseline (768.736 us; speedup 1.0000x reference)
//
#include <hip/hip_runtime.h>

typedef __bf16 bf16;
typedef __bf16 bf16x4 __attribute__((ext_vector_type(4)));
typedef __bf16 bf16x8 __attribute__((ext_vector_type(8)));
typedef float f32x16 __attribute__((ext_vector_type(16)));

#define SCALE 0.17677669529663687f   // 32^-0.5 (HEAD_DIM=32)

__device__ inline f32x16 fzero16() {
  f32x16 v;
  #pragma unroll
  for (int i = 0; i < 16; ++i) v[i] = 0.f;
  return v;
}

// ---------- precompute: M = SCALE * Wq Wk^T, stored as Mqk[b][a] = SCALE*sum_c Wk[b,c]*Wq[a,c]
__global__ __launch_bounds__(256) void k_mqk(const float* __restrict__ W, bf16* __restrict__ Mqk) {
  __shared__ float Wkt[32][65];
  __shared__ float Wqt[32][65];
  const int tb = (blockIdx.x >> 4) * 32;   // b tile
  const int ta = (blockIdx.x & 15) * 32;   // a tile
  const int tid = threadIdx.x;
  const int a_l = tid & 31, b_l = (tid >> 5) * 4;
  float acc[4] = {0.f, 0.f, 0.f, 0.f};
  for (int c0 = 0; c0 < 512; c0 += 64) {
    __syncthreads();
    for (int i = tid; i < 2048; i += 256) {
      int r = i >> 6, c = i & 63;
      Wkt[r][c] = W[(size_t)(tb + r) * 1536 + 512 + c0 + c];
      Wqt[r][c] = W[(size_t)(ta + r) * 1536 + c0 + c];
    }
    __syncthreads();
    for (int c = 0; c < 64; ++c) {
      float wq = Wqt[a_l][c];
      #pragma unroll
      for (int i = 0; i < 4; ++i) acc[i] += Wkt[b_l + i][c] * wq;
    }
  }
  #pragma unroll
  for (int i = 0; i < 4; ++i)
    Mqk[(size_t)(tb + b_l + i) * 512 + ta + a_l] = (bf16)(SCALE * acc[i]);
}

// ---------- precompute: WvT[cout][cin] = Wv[cin][cout]  (bf16)
__global__ __launch_bounds__(256) void k_wvt(const float* __restrict__ W, bf16* __restrict__ WvT) {
  const int cin = blockIdx.x;
  int n = threadIdx.x;
  WvT[(size_t)n * 512 + cin] = (bf16)W[(size_t)cin * 1536 + 1024 + n];
  n += 256;
  WvT[(size_t)n * 512 + cin] = (bf16)W[(size_t)cin * 1536 + 1024 + n];
}

// ---------- precompute: w2[b] = SCALE * sum_c Wk[b,c] * bq[c]   (bias cross-term; only s_j survives softmax)
__global__ __launch_bounds__(256) void k_w2(const float* __restrict__ W, const float* __restrict__ bqkv,
                                            float* __restrict__ w2) {
  __shared__ float red[256];
  const int b = blockIdx.x, tid = threadIdx.x;
  float s = W[(size_t)b * 1536 + 512 + tid] * bqkv[tid]
          + W[(size_t)b * 1536 + 512 + 256 + tid] * bqkv[256 + tid];
  red[tid] = s;
  __syncthreads();
  for (int ofs = 128; ofs > 0; ofs >>= 1) {
    if (tid < ofs) red[tid] += red[tid + ofs];
    __syncthreads();
  }
  if (tid == 0) w2[b] = SCALE * red[0];
}

// ---------- fused per-window kernel ----------
// LDS total = 66560 + 73728 + 13520 + 9216 + 256 = 163280 <= 163840 (gfx950)
struct SMem {
  bf16 Xs[64][520];                                   // X window, bf16, rows>=49 zero; +8 pad for 16B rows
  union { bf16 T1s[64][520]; bf16 Vt[512][72]; } u;   // T1 = X*M (phase 1-2), then V^T (phase 4-5)
  float Ss[52][65];                                   // logits
  bf16 Ps[64][72];                                    // softmax probs (rows>=49 garbage, discarded)
  float sbias[64];                                    // s_j bias term
};

__global__ __launch_bounds__(512, 2) void k_attn(
    const float* __restrict__ x, const float* __restrict__ bqkv,
    const bf16* __restrict__ Mqk, const bf16* __restrict__ WvT,
    const float* __restrict__ w2, float* __restrict__ out) {
  __shared__ SMem sm;
  const int tid = threadIdx.x;
  const int wave = tid >> 6, lane = tid & 63;
  const int lm = lane & 31, hk = lane >> 5;   // 32x32x16 frag: m/n = lane&31, k-group = lane>>5
  const int wid = blockIdx.x;
  const float* xw = x + (size_t)wid * 25088;  // 49*512

  // ---- phase 0: stage X -> LDS bf16, zero pad rows 49..63
  for (int idx = tid; idx < 6272; idx += 512) {       // 49*512/4 float4s
    float4 f = ((const float4*)xw)[idx];
    int row = idx >> 7, c4 = (idx & 127) << 2;
    bf16x4 p;
    p[0] = (bf16)f.x; p[1] = (bf16)f.y; p[2] = (bf16)f.z; p[3] = (bf16)f.w;
    *(bf16x4*)&sm.Xs[row][c4] = p;
  }
  for (int idx = tid; idx < 15 * 130; idx += 512) {
    int r = 49 + idx / 130, c = (idx % 130) * 4;
    bf16x4 z; z[0] = (bf16)0.f; z[1] = (bf16)0.f; z[2] = (bf16)0.f; z[3] = (bf16)0.f;
    *(bf16x4*)&sm.Xs[r][c] = z;
  }
  __syncthreads();

  // ---- phase 1: T1 = X * M  (64x512, k=512). wave w -> cols [64w,64w+64), both 32-row blocks
  {
    const int n_base = wave * 64;
    f32x16 a00 = fzero16(), a01 = fzero16(), a10 = fzero16(), a11 = fzero16();
    const bf16* a0p = &sm.Xs[lm][0];
    const bf16* a1p = &sm.Xs[32 + lm][0];
    const bf16* b0g = Mqk + (size_t)(n_base + lm) * 512;
    const bf16* b1g = Mqk + (size_t)(n_base + 32 + lm) * 512;
    #pragma unroll 4
    for (int k0 = 0; k0 < 512; k0 += 16) {
      const int ko = k0 + 8 * hk;
      bf16x8 fa0 = *(const bf16x8*)(a0p + ko);
      bf16x8 fa1 = *(const bf16x8*)(a1p + ko);
      bf16x8 fb0 = *(const bf16x8*)(b0g + ko);
      bf16x8 fb1 = *(const bf16x8*)(b1g + ko);
      a00 = __builtin_amdgcn_mfma_f32_32x32x16_bf16(fa0, fb0, a00, 0, 0, 0);
      a01 = __builtin_amdgcn_mfma_f32_32x32x16_bf16(fa0, fb1, a01, 0, 0, 0);
      a10 = __builtin_amdgcn_mfma_f32_32x32x16_bf16(fa1, fb0, a10, 0, 0, 0);
      a11 = __builtin_amdgcn_mfma_f32_32x32x16_bf16(fa1, fb1, a11, 0, 0, 0);
    }
    #pragma unroll
    for (int reg = 0; reg < 16; ++reg) {
      const int row = (reg & 3) + 8 * (reg >> 2) + 4 * hk;  // C/D layout [m74/m101]
      sm.u.T1s[row][n_base + lm]           = (bf16)a00[reg];
      sm.u.T1s[row][n_base + 32 + lm]      = (bf16)a01[reg];
      sm.u.T1s[32 + row][n_base + lm]      = (bf16)a10[reg];
      sm.u.T1s[32 + row][n_base + 32 + lm] = (bf16)a11[reg];
    }
  }
  __syncthreads();

  // ---- phase 2: waves 0-3: S = T1 * X^T (64x64, k=512); waves 4-7: sbias_j = X_j . w2
  if (wave < 4) {
    const int r = wave & 1, c = wave >> 1;
    f32x16 accS = fzero16();
    const bf16* ap = &sm.u.T1s[32 * r + lm][0];
    const bf16* bp = &sm.Xs[32 * c + lm][0];   // B[k=b][n=j] = X[j][b]: k-contiguous along Xs row
    #pragma unroll 4
    for (int k0 = 0; k0 < 512; k0 += 16) {
      const int ko = k0 + 8 * hk;
      bf16x8 fa = *(const bf16x8*)(ap + ko);
      bf16x8 fb = *(const bf16x8*)(bp + ko);
      accS = __builtin_amdgcn_mfma_f32_32x32x16_bf16(fa, fb, accS, 0, 0, 0);
    }
    #pragma unroll
    for (int reg = 0; reg < 16; ++reg) {
      const int row = 32 * r + (reg & 3) + 8 * (reg >> 2) + 4 * hk;
      if (row < 52) sm.Ss[row][32 * c + lm] = accS[reg];
    }
  } else {
    const int t2 = tid - 256;
    const int j = t2 >> 2, part = t2 & 3;
    float s = 0.f;
    for (int cc = part * 128; cc < part * 128 + 128; ++cc)
      s += (float)sm.Xs[j][cc] * w2[cc];
    s += __shfl_xor(s, 1);
    s += __shfl_xor(s, 2);
    if (part == 0) sm.sbias[j] = s;
  }
  __syncthreads();

  // ---- phase 3: masked softmax (rows 0..48, cols 0..48), one thread per row
  if (tid < 49) {
    const int i = tid;
    float m = -1e30f;
    for (int j = 0; j < 49; ++j) m = fmaxf(m, sm.Ss[i][j] + sm.sbias[j]);
    float ssum = 0.f;
    for (int j = 0; j < 49; ++j) ssum += __expf(sm.Ss[i][j] + sm.sbias[j] - m);
    const float inv = 1.f / ssum;
    for (int j = 0; j < 49; ++j)
      sm.Ps[i][j] = (bf16)(__expf(sm.Ss[i][j] + sm.sbias[j] - m) * inv);
    for (int j = 49; j < 64; ++j) sm.Ps[i][j] = (bf16)0.f;
  }

  // ---- phase 4: V = X * Wv + bv, written transposed into Vt[chan][token]
  {
    const int n_base = wave * 64;
    f32x16 a00 = fzero16(), a01 = fzero16(), a10 = fzero16(), a11 = fzero16();
    const bf16* a0p = &sm.Xs[lm][0];
    const bf16* a1p = &sm.Xs[32 + lm][0];
    const bf16* b0g = WvT + (size_t)(n_base + lm) * 512;
    const bf16* b1g = WvT + (size_t)(n_base + 32 + lm) * 512;
    #pragma unroll 4
    for (int k0 = 0; k0 < 512; k0 += 16) {
      const int ko = k0 + 8 * hk;
      bf16x8 fa0 = *(const bf16x8*)(a0p + ko);
      bf16x8 fa1 = *(const bf16x8*)(a1p + ko);
      bf16x8 fb0 = *(const bf16x8*)(b0g + ko);
      bf16x8 fb1 = *(const bf16x8*)(b1g + ko);
      a00 = __builtin_amdgcn_mfma_f32_32x32x16_bf16(fa0, fb0, a00, 0, 0, 0);
      a01 = __builtin_amdgcn_mfma_f32_32x32x16_bf16(fa0, fb1, a01, 0, 0, 0);
      a10 = __builtin_amdgcn_mfma_f32_32x32x16_bf16(fa1, fb0, a10, 0, 0, 0);
      a11 = __builtin_amdgcn_mfma_f32_32x32x16_bf16(fa1, fb1, a11, 0, 0, 0);
    }
    const float bv0 = bqkv[1024 + n_base + lm];
    const float bv1 = bqkv[1024 + n_base + 32 + lm];
    #pragma unroll
    for (int g = 0; g < 4; ++g) {
      const int t0 = 8 * g + 4 * hk;   // 4 consecutive token rows per reg-group
      bf16x4 p0, p1, p2, p3;
      #pragma unroll
      for (int j = 0; j < 4; ++j) {
        p0[j] = (bf16)(a00[4 * g + j] + bv0);
        p1[j] = (bf16)(a01[4 * g + j] + bv1);
        p2[j] = (bf16)(a10[4 * g + j] + bv0);
        p3[j] = (bf16)(a11[4 * g + j] + bv1);
      }
      *(bf16x4*)&sm.u.Vt[n_base + lm][t0]           = p0;
      *(bf16x4*)&sm.u.Vt[n_base + 32 + lm][t0]      = p1;
      *(bf16x4*)&sm.u.Vt[n_base + lm][32 + t0]      = p2;
      *(bf16x4*)&sm.u.Vt[n_base + 32 + lm][32 + t0] = p3;
    }
  }
  __syncthreads();

  // ---- phase 5: O = P * V (64x512, k=64), store f32 rows < 49
  {
    const int n_base = wave * 64;
    f32x16 a00 = fzero16(), a01 = fzero16(), a10 = fzero16(), a11 = fzero16();
    #pragma unroll
    for (int k0 = 0; k0 < 64; k0 += 16) {
      const int ko = k0 + 8 * hk;
      bf16x8 fa0 = *(const bf16x8*)&sm.Ps[lm][ko];
      bf16x8 fa1 = *(const bf16x8*)&sm.Ps[32 + lm][ko];
      bf16x8 fb0 = *(const bf16x8*)&sm.u.Vt[n_base + lm][ko];
      bf16x8 fb1 = *(const bf16x8*)&sm.u.Vt[n_base + 32 + lm][ko];
      a00 = __builtin_amdgcn_mfma_f32_32x32x16_bf16(fa0, fb0, a00, 0, 0, 0);
      a01 = __builtin_amdgcn_mfma_f32_32x32x16_bf16(fa0, fb1, a01, 0, 0, 0);
      a10 = __builtin_amdgcn_mfma_f32_32x32x16_bf16(fa1, fb0, a10, 0, 0, 0);
      a11 = __builtin_amdgcn_mfma_f32_32x32x16_bf16(fa1, fb1, a11, 0, 0, 0);
    }
    float* ow = out + (size_t)wid * 25088;
    const int c0_ = n_base + lm, c1_ = n_base + 32 + lm;
    #pragma unroll
    for (int reg = 0; reg < 16; ++reg) {
      const int row = (reg & 3) + 8 * (reg >> 2) + 4 * hk;
      if (row < 49) {
        ow[row * 512 + c0_] = a00[reg];
        ow[row * 512 + c1_] = a01[reg];
      }
      const int row1 = 32 + row;
      if (row1 < 49) {
        ow[row1 * 512 + c0_] = a10[reg];
        ow[row1 * 512 + c1_] = a11[reg];
      }
    }
  }
}

extern "C" void kernel_launch(void* const* d_in, const int* in_sizes, int n_in,
                              void* d_out, int out_size, void* d_ws, size_t ws_size,
                              hipStream_t stream) {
  const float* x    = (const float*)d_in[0];
  // d_in[1] (x_all) is unused by the reference
  const float* W    = (const float*)d_in[2];
  const float* bqkv = (const float*)d_in[3];
  float* out = (float*)d_out;

  bf16*  Mqk = (bf16*)d_ws;                                    // 512*512*2 = 512 KB
  bf16*  WvT = (bf16*)((char*)d_ws + 512 * 512 * 2);           // 512 KB
  float* w2  = (float*)((char*)d_ws + 2 * 512 * 512 * 2);      // 2 KB

  k_mqk<<<256, 256, 0, stream>>>(W, Mqk);
  k_wvt<<<512, 256, 0, stream>>>(W, WvT);
  k_w2 <<<512, 256, 0, stream>>>(W, bqkv, w2);
  k_attn<<<2048, 512, 0, stream>>>(x, bqkv, Mqk, WvT, w2, out);
}